// Round 7
// baseline (49.739 us; speedup 1.0000x reference)
//
#include <hip/hip_runtime.h>

#define N 768
#define H 128
#define NM1 767
#define LDSW (H + 4)   // rows shift 4 banks: uu broadcast, vv 2-way (free)
#define MAGIC 0x5EC7BEEFu

union Smem {
  float zsh[3][H];                                   // phase A
  struct { float ush[48 * LDSW]; float vsh[48 * LDSW]; } b;  // phase B
};

__global__ __launch_bounds__(256) void fused_flag_kernel(
    const float* __restrict__ z, const float* __restrict__ W1,
    const float* __restrict__ b1, const float* __restrict__ w2,
    const float* __restrict__ b2, float* __restrict__ U,
    float* __restrict__ Vb, unsigned int* __restrict__ flags,
    float* __restrict__ out) {
  __shared__ Smem sm;
  const int t = threadIdx.x;
  const int blk = blockIdx.x;

  // ---------- Phase A: U/Vb rows [3*blk, 3*blk+3) ----------
  {
    const int r0 = 3 * blk;
    if (t < 96) {
      const int r = t >> 5, c4 = t & 31;
      ((float4*)sm.zsh[r])[c4] = ((const float4*)(z + (size_t)(r0 + r) * H))[c4];
    }
    __syncthreads();
    const int k = t & (H - 1);       // output channel (lanes consecutive -> coalesced stores)
    const int half = t >> 7;         // 0 -> U, 1 -> Vb (wave-uniform)
    const float* __restrict__ wrow = W1 + (size_t)k * (2 * H) + half * H;
    float a0 = 0.f, a1 = 0.f, a2 = 0.f;
#pragma unroll 4                     // cap: full unroll spills (R2 lesson)
    for (int m = 0; m < H; m += 4) {
      const float4 w  = *(const float4*)(wrow + m);   // per-lane own 512B row stream
      const float4 z0 = *(const float4*)&sm.zsh[0][m];
      const float4 z1 = *(const float4*)&sm.zsh[1][m];
      const float4 z2 = *(const float4*)&sm.zsh[2][m];
      a0 = fmaf(w.x, z0.x, a0); a0 = fmaf(w.y, z0.y, a0);
      a0 = fmaf(w.z, z0.z, a0); a0 = fmaf(w.w, z0.w, a0);
      a1 = fmaf(w.x, z1.x, a1); a1 = fmaf(w.y, z1.y, a1);
      a1 = fmaf(w.z, z1.z, a1); a1 = fmaf(w.w, z1.w, a1);
      a2 = fmaf(w.x, z2.x, a2); a2 = fmaf(w.y, z2.y, a2);
      a2 = fmaf(w.z, z2.z, a2); a2 = fmaf(w.w, z2.w, a2);
    }
    const float bias = half ? b1[k] : 0.f;
    float* dst = half ? Vb : U;
    dst[(size_t)(r0 + 0) * H + k] = a0 + bias;
    dst[(size_t)(r0 + 1) * H + k] = a1 + bias;
    dst[(size_t)(r0 + 2) * H + k] = a2 + bias;
    __threadfence();                 // device-scope release of this thread's stores
    __syncthreads();                 // all threads' fences precede the flag
    if (t == 0)
      __hip_atomic_store(&flags[blk], MAGIC, __ATOMIC_RELEASE, __HIP_MEMORY_SCOPE_AGENT);
  }

  // ---------- Wait for the 32 producer blocks this tile needs ----------
  const int ti = blk >> 4, tj = blk & 15;
  if (t < 32) {
    const int p = (t < 16) ? (16 * ti + t) : (16 * tj + (t - 16));
    while (__hip_atomic_load(&flags[p], __ATOMIC_ACQUIRE, __HIP_MEMORY_SCOPE_AGENT) != MAGIC)
      __builtin_amdgcn_s_sleep(1);
  }
  __syncthreads();

  // ---------- Phase B: 48x48 tile, 3x3 regs/thread (R3's proven p2) ----------
  {
    const int bi = ti * 48, bj = tj * 48;
#pragma unroll
    for (int l = t; l < 48 * 32; l += 256) {
      const int r = l >> 5, c4 = l & 31;
      *(float4*)&sm.b.ush[r * LDSW + c4 * 4] = ((const float4*)(U  + (size_t)(bi + r) * H))[c4];
      *(float4*)&sm.b.vsh[r * LDSW + c4 * 4] = ((const float4*)(Vb + (size_t)(bj + r) * H))[c4];
    }
    __syncthreads();
    const int tx = t & 15, ty = t >> 4;
    float acc[3][3] = {};
#pragma unroll 8
    for (int k = 0; k < H; k += 4) {
      const float4 w = *(const float4*)(w2 + k);   // uniform -> scalar load
      float4 uu[3], vv[3];
#pragma unroll
      for (int r = 0; r < 3; ++r) uu[r] = *(const float4*)&sm.b.ush[(ty + 16 * r) * LDSW + k];
#pragma unroll
      for (int r = 0; r < 3; ++r) vv[r] = *(const float4*)&sm.b.vsh[(tx + 16 * r) * LDSW + k];
#pragma unroll
      for (int a = 0; a < 3; ++a)
#pragma unroll
        for (int b = 0; b < 3; ++b) {
          acc[a][b] = fmaf(fmaxf(uu[a].x + vv[b].x, 0.f), w.x, acc[a][b]);
          acc[a][b] = fmaf(fmaxf(uu[a].y + vv[b].y, 0.f), w.y, acc[a][b]);
          acc[a][b] = fmaf(fmaxf(uu[a].z + vv[b].z, 0.f), w.z, acc[a][b]);
          acc[a][b] = fmaf(fmaxf(uu[a].w + vv[b].w, 0.f), w.w, acc[a][b]);
        }
    }
    const float bb = b2[0];
#pragma unroll
    for (int a = 0; a < 3; ++a) {
      const int i = bi + ty + 16 * a;
#pragma unroll
      for (int b = 0; b < 3; ++b) {
        const int j = bj + tx + 16 * b;
        if (i != j) out[(size_t)i * NM1 + j - (j > i ? 1 : 0)] = acc[a][b] + bb;
      }
    }
  }
}

extern "C" void kernel_launch(void* const* d_in, const int* in_sizes, int n_in,
                              void* d_out, int out_size, void* d_ws, size_t ws_size,
                              hipStream_t stream) {
  const float* z  = (const float*)d_in[0];
  const float* W1 = (const float*)d_in[1];
  const float* b1 = (const float*)d_in[2];
  const float* W2 = (const float*)d_in[3];
  const float* b2 = (const float*)d_in[4];
  float* U  = (float*)d_ws;
  float* Vb = U + N * H;
  unsigned int* flags = (unsigned int*)(Vb + N * H);
  float* out = (float*)d_out;
  fused_flag_kernel<<<256, 256, 0, stream>>>(z, W1, b1, W2, b2, U, Vb, flags, out);
}